// Round 1
// baseline (3329.882 us; speedup 1.0000x reference)
//
#include <hip/hip_runtime.h>
#include <math.h>

typedef _Float16 f16;
typedef _Float16 f16x8 __attribute__((ext_vector_type(8)));
typedef float f32x4 __attribute__((ext_vector_type(4)));

#define MFMA16(A_, B_, C_) __builtin_amdgcn_mfma_f32_16x16x32_f16((A_), (B_), (C_), 0, 0, 0)

__device__ __forceinline__ float sigf(float x) { return 1.0f / (1.0f + __expf(-x)); }
__device__ __forceinline__ float tanhf_(float x) { float e = __expf(2.0f * x); return 1.0f - 2.0f / (e + 1.0f); }

// ---------------- workspace layout (bytes) ----------------
static const size_t OFF_ENCIN = 0;                         // f16 [1024][256][32]
static const size_t OFF_DECIN = 16777216;                  // f16 [48][256][32]
static const size_t OFF_WENC  = OFF_DECIN + 786432;        // f16 [9][48][64][8]
static const size_t OFF_WDEC  = OFF_WENC + 442368;         // f16 [9][48][64][8]
static const size_t OFF_W32   = OFF_WDEC + 442368;         // float[768]
static const size_t OFF_BE    = OFF_W32 + 3072;            // float[1024]
static const size_t OFF_BD    = OFF_BE + 4096;             // float[1024]
static const size_t OFF_HENC  = OFF_BD + 4096;             // f16 [256][256]
static const size_t OFF_EOUT  = OFF_HENC + 131072;         // float[256]
static const size_t OFF_XST   = OFF_EOUT + 1024;           // float[48][32][2]
static const size_t OFF_OST   = OFF_XST + 12288;           // float[96]
static const size_t OFF_BAR   = OFF_OST + 512;             // int[2]

struct P {
  const float *Xe, *Xd, *Xge, *Xgd, *Wge, *bge, *Wgd, *bgd;
  const float *eWih, *eWhh, *ebih, *ebhh, *eWo, *ebo;
  const float *dWih, *dWhh, *dbih, *dbhh, *dWo, *dbo;
  const float *bn1g, *bn1b, *bnTg, *bnTb;
  f16 *encin, *decin, *wencf, *wdecf;
  float *w32, *bE, *bD;
  f16 *henc;
  float *eout, *xst, *ost;
  int *bar;
  float *out;
};

// ---------------- prep kernels ----------------
__global__ void prep1(P p) {
  const int blk = blockIdx.x, tid = threadIdx.x;
  __shared__ float swg[512];
  __shared__ float sbg[16];
  if (blk < 1024) {                       // enc_in: i = b*1024 + t
    for (int i = tid; i < 512; i += 256) swg[i] = p.Wge[i];
    if (tid < 16) sbg[tid] = p.bge[tid];
    __syncthreads();
    const int i = blk * 256 + tid;
    const int b = i >> 10, t = i & 1023;
    const float* xg = p.Xge + (size_t)(b * 1024 + t) * 32;
    const float* xe = p.Xe + (size_t)(b * 1024 + t) * 16;
    f16* o = p.encin + (size_t)(t * 256 + b) * 32;
    float xgv[32];
#pragma unroll
    for (int k = 0; k < 32; ++k) xgv[k] = xg[k];
#pragma unroll
    for (int c = 0; c < 16; ++c) o[c] = (f16)xe[c];
#pragma unroll 4
    for (int r = 0; r < 16; ++r) {
      float acc = sbg[r];
#pragma unroll
      for (int k = 0; k < 32; ++k) acc += swg[r * 32 + k] * xgv[k];
      o[16 + r] = (f16)acc;
    }
  } else if (blk < 1072) {                // dec_in: i = b*48 + t
    for (int i = tid; i < 512; i += 256) swg[i] = p.Wgd[i];
    if (tid < 16) sbg[tid] = p.bgd[tid];
    __syncthreads();
    const int i = (blk - 1024) * 256 + tid;
    const int b = i / 48, t = i - b * 48;
    const float* xg = p.Xgd + (size_t)(b * 48 + t) * 32;
    const float* xd = p.Xd + (size_t)(b * 48 + t) * 16;
    f16* o = p.decin + (size_t)(t * 256 + b) * 32;
    float xgv[32];
#pragma unroll
    for (int k = 0; k < 32; ++k) xgv[k] = xg[k];
#pragma unroll
    for (int c = 0; c < 16; ++c) o[c] = (f16)xd[c];
#pragma unroll 4
    for (int r = 0; r < 16; ++r) {
      float acc = sbg[r];
#pragma unroll
      for (int k = 0; k < 32; ++k) acc += swg[r * 32 + k] * xgv[k];
      o[16 + r] = (f16)acc;
    }
  } else if (blk < 1180) {                // encoder weight fragments
    const int i = (blk - 1072) * 256 + tid;     // [0, 27648)
    const int kt = i / 3072, r2 = i - kt * 3072;
    const int nt = r2 >> 6, l = r2 & 63;
    const int n = nt * 16 + (l & 15), g = l >> 4;
    f16* o = p.wencf + (size_t)i * 8;
#pragma unroll
    for (int j = 0; j < 8; ++j) {
      const int k = g * 8 + j;
      o[j] = (f16)((kt == 0) ? p.eWih[n * 32 + k] : p.eWhh[n * 256 + (kt - 1) * 32 + k]);
    }
  } else if (blk < 1288) {                // decoder weight fragments
    const int i = (blk - 1180) * 256 + tid;
    const int kt = i / 3072, r2 = i - kt * 3072;
    const int nt = r2 >> 6, l = r2 & 63;
    const int n = nt * 16 + (l & 15), g = l >> 4;
    f16* o = p.wdecf + (size_t)i * 8;
#pragma unroll
    for (int j = 0; j < 8; ++j) {
      const int k = g * 8 + j;
      o[j] = (f16)((kt == 0) ? p.dWih[n * 33 + k] : p.dWhh[n * 256 + (kt - 1) * 32 + k]);
    }
  } else if (blk == 1288) {               // w32 column + zero stats/barrier
    for (int i = tid; i < 768; i += 256) p.w32[i] = p.dWih[i * 33 + 32];
    for (int i = tid; i < 96; i += 256) p.ost[i] = 0.f;
    if (tid == 0) { p.bar[0] = 0; p.bar[1] = 0; }
  } else if (blk == 1289) {               // encoder combined biases
    for (int i = tid; i < 1024; i += 256) {
      float v;
      if (i < 512) v = p.ebih[i] + p.ebhh[i];
      else if (i < 768) v = p.ebih[i];
      else v = p.ebhh[i - 256];
      p.bE[i] = v;
    }
  } else {                                // decoder combined biases
    for (int i = tid; i < 1024; i += 256) {
      float v;
      if (i < 512) v = p.dbih[i] + p.dbhh[i];
      else if (i < 768) v = p.dbih[i];
      else v = p.dbhh[i - 256];
      p.bD[i] = v;
    }
  }
}

__global__ void prep2(P p) {              // decoder x-channel BN stats per step
  const int i = blockIdx.x * 256 + threadIdx.x;
  if (i >= 48 * 32) return;
  const int s = i >> 5, c = i & 31;
  float s1 = 0.f, s2 = 0.f;
  for (int b = 0; b < 256; ++b) {
    const float v = (float)p.decin[(size_t)(s * 256 + b) * 32 + c];
    s1 += v; s2 += v * v;
  }
  const float mu = s1 * (1.0f / 256.0f);
  p.xst[i * 2] = mu;
  p.xst[i * 2 + 1] = s2 * (1.0f / 256.0f) - mu * mu;
}

// ---------------- device barrier (16 WGs) ----------------
__device__ __forceinline__ void gridbar(int* bar) {
  __syncthreads();
  if (threadIdx.x == 0) {
    const int g = __hip_atomic_load(&bar[1], __ATOMIC_ACQUIRE, __HIP_MEMORY_SCOPE_AGENT);
    const int a = __hip_atomic_fetch_add(&bar[0], 1, __ATOMIC_ACQ_REL, __HIP_MEMORY_SCOPE_AGENT);
    if (a == 15) {
      __hip_atomic_store(&bar[0], 0, __ATOMIC_RELAXED, __HIP_MEMORY_SCOPE_AGENT);
      __hip_atomic_store(&bar[1], g + 1, __ATOMIC_RELEASE, __HIP_MEMORY_SCOPE_AGENT);
    } else {
      while (__hip_atomic_load(&bar[1], __ATOMIC_ACQUIRE, __HIP_MEMORY_SCOPE_AGENT) == g) {
        __builtin_amdgcn_s_sleep(2);
      }
    }
  }
  __syncthreads();
}

// ---------------- encoder: 16 WGs x 512 thr, 1024 steps ----------------
__global__ __launch_bounds__(512, 2) void enc_kernel(P p) {
  __shared__ f16 sWL[49152];     // W k-tiles 7,8 (98304 B)
  __shared__ f16 sH[8192];       // h double buffer, swizzled (16384 B)
  __shared__ float sRed[512];
  const int tid = threadIdx.x;
  const int l = tid & 63, w = tid >> 6;
  const int g = l >> 4, m16 = l & 15;
  const int sw16 = (m16 & 7) << 4;
  const int bg = blockIdx.x * 16;

  { // stage LDS W (kts 7,8)
    const int4* src = (const int4*)(p.wencf + 172032);
    int4* dst = (int4*)sWL;
#pragma unroll
    for (int i = 0; i < 12; ++i) dst[tid + i * 512] = src[tid + i * 512];
  }
  { // zero h buffers
    int* hz = (int*)sH;
#pragma unroll
    for (int i = 0; i < 8; ++i) hz[tid + i * 512] = 0;
  }
  const int nts[6] = {w, 8 + w, 16 + w, 24 + w, 32 + w, 40 + w};
  f16x8 Wr[7][6];
#pragma unroll
  for (int kt = 0; kt < 7; ++kt)
#pragma unroll
    for (int i = 0; i < 6; ++i)
      Wr[kt][i] = *(const f16x8*)(p.wencf + ((size_t)(kt * 48 + nts[i]) * 64 + l) * 8);
  const int J1 = 16 * w + m16, J2 = 128 + J1;
  const float br1 = p.bE[J1], bz1 = p.bE[256 + J1], bi1 = p.bE[512 + J1], bh1 = p.bE[768 + J1];
  const float br2 = p.bE[J2], bz2 = p.bE[256 + J2], bi2 = p.bE[512 + J2], bh2 = p.bE[768 + J2];
  __syncthreads();

  int ph = 0;
  f16x8 xf = *(const f16x8*)(p.encin + (size_t)(bg + m16) * 32 + 8 * g);
#pragma unroll 1
  for (int t = 0; t < 1024; ++t) {
    const int tn = (t < 1023) ? t + 1 : t;
    const f16x8 xn = *(const f16x8*)(p.encin + (size_t)(tn * 256 + bg + m16) * 32 + 8 * g);
    f32x4 aR0 = {0,0,0,0}, aR1 = {0,0,0,0}, aZ0 = {0,0,0,0}, aZ1 = {0,0,0,0};
    f32x4 aNi0 = {0,0,0,0}, aNi1 = {0,0,0,0}, aNh0 = {0,0,0,0}, aNh1 = {0,0,0,0};
    // kt0: x part
    aR0 = MFMA16(xf, Wr[0][0], aR0);
    aR1 = MFMA16(xf, Wr[0][1], aR1);
    aZ0 = MFMA16(xf, Wr[0][2], aZ0);
    aZ1 = MFMA16(xf, Wr[0][3], aZ1);
    aNi0 = MFMA16(xf, Wr[0][4], aNi0);
    aNi1 = MFMA16(xf, Wr[0][5], aNi1);
    // kts 1..6: h part, W in registers
#pragma unroll
    for (int kk = 1; kk <= 6; ++kk) {
      const f16x8 a = *(const f16x8*)((const char*)sH + ph * 8192 + m16 * 512 +
                                      ((64 * (kk - 1) + 16 * g) ^ sw16));
      aR0 = MFMA16(a, Wr[kk][0], aR0);
      aR1 = MFMA16(a, Wr[kk][1], aR1);
      aZ0 = MFMA16(a, Wr[kk][2], aZ0);
      aZ1 = MFMA16(a, Wr[kk][3], aZ1);
      aNh0 = MFMA16(a, Wr[kk][4], aNh0);
      aNh1 = MFMA16(a, Wr[kk][5], aNh1);
    }
    // kts 7,8: h part, W in LDS
#pragma unroll
    for (int kk = 7; kk <= 8; ++kk) {
      const f16x8 a = *(const f16x8*)((const char*)sH + ph * 8192 + m16 * 512 +
                                      ((64 * (kk - 1) + 16 * g) ^ sw16));
      const char* wb = (const char*)sWL + (kk - 7) * 49152;
      const f16x8 q0 = *(const f16x8*)(wb + (nts[0] * 64 + l) * 16);
      const f16x8 q1 = *(const f16x8*)(wb + (nts[1] * 64 + l) * 16);
      const f16x8 q2 = *(const f16x8*)(wb + (nts[2] * 64 + l) * 16);
      const f16x8 q3 = *(const f16x8*)(wb + (nts[3] * 64 + l) * 16);
      const f16x8 q4 = *(const f16x8*)(wb + (nts[4] * 64 + l) * 16);
      const f16x8 q5 = *(const f16x8*)(wb + (nts[5] * 64 + l) * 16);
      aR0 = MFMA16(a, q0, aR0);
      aR1 = MFMA16(a, q1, aR1);
      aZ0 = MFMA16(a, q2, aZ0);
      aZ1 = MFMA16(a, q3, aZ1);
      aNh0 = MFMA16(a, q4, aNh0);
      aNh1 = MFMA16(a, q5, aNh1);
    }
    // epilogue: gates -> new h (buffer ph^1)
    {
      char* hw = (char*)sH + (ph ^ 1) * 8192;
      const char* hr = (const char*)sH + ph * 8192;
#pragma unroll
      for (int q = 0; q < 4; ++q) {
        const int m = 4 * g + q;
        const int sw = (m & 7) << 4;
        const float h1 = (float)*(const f16*)(hr + m * 512 + ((2 * J1) ^ sw));
        const float r1 = sigf(aR0[q] + br1);
        const float z1 = sigf(aZ0[q] + bz1);
        const float n1 = tanhf_(aNi0[q] + bi1 + r1 * (aNh0[q] + bh1));
        *(f16*)(hw + m * 512 + ((2 * J1) ^ sw)) = (f16)((1.0f - z1) * n1 + z1 * h1);
        const float h2 = (float)*(const f16*)(hr + m * 512 + ((2 * J2) ^ sw));
        const float r2 = sigf(aR1[q] + br2);
        const float z2 = sigf(aZ1[q] + bz2);
        const float n2 = tanhf_(aNi1[q] + bi2 + r2 * (aNh1[q] + bh2));
        *(f16*)(hw + m * 512 + ((2 * J2) ^ sw)) = (f16)((1.0f - z2) * n2 + z2 * h2);
      }
    }
    __syncthreads();
    ph ^= 1;
    xf = xn;
  }
  // finalize: store h, compute enc_out
  {
    const char* hb = (const char*)sH + ph * 8192;
    const int m = tid & 15, grp = tid >> 4;
    const f16x8 hv = *(const f16x8*)(hb + m * 512 + ((16 * grp) ^ ((m & 7) << 4)));
    *(f16x8*)(p.henc + (size_t)(bg + m) * 256 + 8 * grp) = hv;
    float part = 0.f;
#pragma unroll
    for (int jj = 0; jj < 8; ++jj) part += (float)hv[jj] * p.eWo[8 * grp + jj];
    sRed[m * 32 + grp] = part;
    __syncthreads();
    if (tid < 16) {
      float o = p.ebo[0];
#pragma unroll 8
      for (int k = 0; k < 32; ++k) o += sRed[tid * 32 + k];
      p.eout[bg + tid] = o;
    }
  }
}

// ---------------- decoder: 16 WGs x 512 thr, 48 steps + BN barrier ----------------
__global__ __launch_bounds__(512, 2) void dec_kernel(P p) {
  __shared__ f16 sWL[49152];
  __shared__ f16 sH[8192];
  __shared__ f16 sDin[1024];     // [16][64] f16, swizzled; cols 33..63 zero
  __shared__ float sRed[512];
  __shared__ float sOutv[16];
  __shared__ float sO32[16];
  const int tid = threadIdx.x;
  const int l = tid & 63, w = tid >> 6;
  const int g = l >> 4, m16 = l & 15;
  const int sw16 = (m16 & 7) << 4;
  const int bg = blockIdx.x * 16;

  { // stage LDS W (kts 7,8)
    const int4* src = (const int4*)(p.wdecf + 172032);
    int4* dst = (int4*)sWL;
#pragma unroll
    for (int i = 0; i < 12; ++i) dst[tid + i * 512] = src[tid + i * 512];
  }
  { // h <- h_enc (swizzled), buffer 0
    const int m = tid & 15, grp = tid >> 4;
    const f16x8 hv = *(const f16x8*)(p.henc + (size_t)(bg + m) * 256 + 8 * grp);
    *(f16x8*)((char*)sH + m * 512 + ((16 * grp) ^ ((m & 7) << 4))) = hv;
  }
  if (tid < 128) ((int4*)sDin)[tid] = int4{0, 0, 0, 0};
  const int nts[6] = {w, 8 + w, 16 + w, 24 + w, 32 + w, 40 + w};
  f16x8 Wr[7][6];
#pragma unroll
  for (int kt = 0; kt < 7; ++kt)
#pragma unroll
    for (int i = 0; i < 6; ++i)
      Wr[kt][i] = *(const f16x8*)(p.wdecf + ((size_t)(kt * 48 + nts[i]) * 64 + l) * 8);
  const int J1 = 16 * w + m16, J2 = 128 + J1;
  const float br1 = p.bD[J1], bz1 = p.bD[256 + J1], bi1 = p.bD[512 + J1], bh1 = p.bD[768 + J1];
  const float br2 = p.bD[J2], bz2 = p.bD[256 + J2], bi2 = p.bD[512 + J2], bh2 = p.bD[768 + J2];
  const float w32r1 = p.w32[J1], w32z1 = p.w32[256 + J1], w32n1 = p.w32[512 + J1];
  const float w32r2 = p.w32[J2], w32z2 = p.w32[256 + J2], w32n2 = p.w32[512 + J2];
  __syncthreads();

  // ---- BN_1: dinp0 = BN(concat(dec_wg[:,0], enc_out)) ----
  {
    if (tid < 16) sOutv[tid] = p.eout[bg + tid];
    __syncthreads();
    if (tid == 0) {
      float s1 = 0.f, s2 = 0.f;
#pragma unroll
      for (int k = 0; k < 16; ++k) { const float v = sOutv[k]; s1 += v; s2 += v * v; }
      atomicAdd(&p.ost[0], s1);
      atomicAdd(&p.ost[1], s2);
    }
    gridbar(p.bar);
    if (tid < 16) {
      const float S1 = __hip_atomic_load(&p.ost[0], __ATOMIC_RELAXED, __HIP_MEMORY_SCOPE_AGENT);
      const float S2 = __hip_atomic_load(&p.ost[1], __ATOMIC_RELAXED, __HIP_MEMORY_SCOPE_AGENT);
      const float mu = S1 * (1.0f / 256.0f);
      const float var = S2 * (1.0f / 256.0f) - mu * mu;
      sO32[tid] = p.bn1g[32] * (sOutv[tid] - mu) / sqrtf(var + 1e-5f) + p.bn1b[32];
    }
    {
      const int m = tid & 15, c = tid >> 4;
      const float x = (float)p.decin[(size_t)(bg + m) * 32 + c];
      const float mx = p.xst[c * 2], vx = p.xst[c * 2 + 1];
      const float v = p.bn1g[c] * (x - mx) / sqrtf(vx + 1e-5f) + p.bn1b[c];
      *(f16*)((char*)sDin + m * 128 + ((2 * c) ^ ((m & 7) << 4))) = (f16)v;
    }
    __syncthreads();
  }

  int ph = 0;
#pragma unroll 1
  for (int t = 0; t < 48; ++t) {
    f32x4 aR0 = {0,0,0,0}, aR1 = {0,0,0,0}, aZ0 = {0,0,0,0}, aZ1 = {0,0,0,0};
    f32x4 aNi0 = {0,0,0,0}, aNi1 = {0,0,0,0}, aNh0 = {0,0,0,0}, aNh1 = {0,0,0,0};
    { // kt0: dinp (channels 0..31)
      const f16x8 a = *(const f16x8*)((const char*)sDin + m16 * 128 + ((16 * g) ^ sw16));
      aR0 = MFMA16(a, Wr[0][0], aR0);
      aR1 = MFMA16(a, Wr[0][1], aR1);
      aZ0 = MFMA16(a, Wr[0][2], aZ0);
      aZ1 = MFMA16(a, Wr[0][3], aZ1);
      aNi0 = MFMA16(a, Wr[0][4], aNi0);
      aNi1 = MFMA16(a, Wr[0][5], aNi1);
    }
#pragma unroll
    for (int kk = 1; kk <= 6; ++kk) {
      const f16x8 a = *(const f16x8*)((const char*)sH + ph * 8192 + m16 * 512 +
                                      ((64 * (kk - 1) + 16 * g) ^ sw16));
      aR0 = MFMA16(a, Wr[kk][0], aR0);
      aR1 = MFMA16(a, Wr[kk][1], aR1);
      aZ0 = MFMA16(a, Wr[kk][2], aZ0);
      aZ1 = MFMA16(a, Wr[kk][3], aZ1);
      aNh0 = MFMA16(a, Wr[kk][4], aNh0);
      aNh1 = MFMA16(a, Wr[kk][5], aNh1);
    }
#pragma unroll
    for (int kk = 7; kk <= 8; ++kk) {
      const f16x8 a = *(const f16x8*)((const char*)sH + ph * 8192 + m16 * 512 +
                                      ((64 * (kk - 1) + 16 * g) ^ sw16));
      const char* wb = (const char*)sWL + (kk - 7) * 49152;
      const f16x8 q0 = *(const f16x8*)(wb + (nts[0] * 64 + l) * 16);
      const f16x8 q1 = *(const f16x8*)(wb + (nts[1] * 64 + l) * 16);
      const f16x8 q2 = *(const f16x8*)(wb + (nts[2] * 64 + l) * 16);
      const f16x8 q3 = *(const f16x8*)(wb + (nts[3] * 64 + l) * 16);
      const f16x8 q4 = *(const f16x8*)(wb + (nts[4] * 64 + l) * 16);
      const f16x8 q5 = *(const f16x8*)(wb + (nts[5] * 64 + l) * 16);
      aR0 = MFMA16(a, q0, aR0);
      aR1 = MFMA16(a, q1, aR1);
      aZ0 = MFMA16(a, q2, aZ0);
      aZ1 = MFMA16(a, q3, aZ1);
      aNh0 = MFMA16(a, q4, aNh0);
      aNh1 = MFMA16(a, q5, aNh1);
    }
    // epilogue with rank-1 out-channel term
    {
      char* hw = (char*)sH + (ph ^ 1) * 8192;
      const char* hr = (const char*)sH + ph * 8192;
#pragma unroll
      for (int q = 0; q < 4; ++q) {
        const int m = 4 * g + q;
        const int sw = (m & 7) << 4;
        const float o32m = sO32[m];
        const float h1 = (float)*(const f16*)(hr + m * 512 + ((2 * J1) ^ sw));
        const float r1 = sigf(aR0[q] + br1 + o32m * w32r1);
        const float z1 = sigf(aZ0[q] + bz1 + o32m * w32z1);
        const float n1 = tanhf_(aNi0[q] + bi1 + o32m * w32n1 + r1 * (aNh0[q] + bh1));
        *(f16*)(hw + m * 512 + ((2 * J1) ^ sw)) = (f16)((1.0f - z1) * n1 + z1 * h1);
        const float h2 = (float)*(const f16*)(hr + m * 512 + ((2 * J2) ^ sw));
        const float r2 = sigf(aR1[q] + br2 + o32m * w32r2);
        const float z2 = sigf(aZ1[q] + bz2 + o32m * w32z2);
        const float n2 = tanhf_(aNi1[q] + bi2 + o32m * w32n2 + r2 * (aNh1[q] + bh2));
        *(f16*)(hw + m * 512 + ((2 * J2) ^ sw)) = (f16)((1.0f - z2) * n2 + z2 * h2);
      }
    }
    __syncthreads();   // h_new complete
    // out = h_new @ Wo + bo
    {
      const int m = tid & 15, grp = tid >> 4;
      const char* hb = (const char*)sH + (ph ^ 1) * 8192;
      const f16x8 hv = *(const f16x8*)(hb + m * 512 + ((16 * grp) ^ ((m & 7) << 4)));
      float part = 0.f;
#pragma unroll
      for (int jj = 0; jj < 8; ++jj) part += (float)hv[jj] * p.dWo[8 * grp + jj];
      sRed[m * 32 + grp] = part;
    }
    __syncthreads();
    if (tid < 16) {
      float o = p.dbo[0];
#pragma unroll 8
      for (int k = 0; k < 32; ++k) o += sRed[tid * 32 + k];
      p.out[(size_t)(bg + tid) * 48 + t] = o;
      sOutv[tid] = o;
    }
    if (t < 47) {
      __syncthreads();  // sOutv visible
      if (tid == 0) {
        float s1 = 0.f, s2 = 0.f;
#pragma unroll
        for (int k = 0; k < 16; ++k) { const float v = sOutv[k]; s1 += v; s2 += v * v; }
        atomicAdd(&p.ost[(t + 1) * 2 + 0], s1);
        atomicAdd(&p.ost[(t + 1) * 2 + 1], s2);
      }
      gridbar(p.bar);
      if (tid < 16) {
        const float S1 = __hip_atomic_load(&p.ost[(t + 1) * 2 + 0], __ATOMIC_RELAXED, __HIP_MEMORY_SCOPE_AGENT);
        const float S2 = __hip_atomic_load(&p.ost[(t + 1) * 2 + 1], __ATOMIC_RELAXED, __HIP_MEMORY_SCOPE_AGENT);
        const float mu = S1 * (1.0f / 256.0f);
        const float var = S2 * (1.0f / 256.0f) - mu * mu;
        sO32[tid] = p.bnTg[t * 33 + 32] * (sOutv[tid] - mu) / sqrtf(var + 1e-5f) + p.bnTb[t * 33 + 32];
      }
      {
        const int m = tid & 15, c = tid >> 4;
        const int s = t + 1;
        const float x = (float)p.decin[(size_t)(s * 256 + bg + m) * 32 + c];
        const float mx = p.xst[(s * 32 + c) * 2], vx = p.xst[(s * 32 + c) * 2 + 1];
        const float v = p.bnTg[t * 33 + c] * (x - mx) / sqrtf(vx + 1e-5f) + p.bnTb[t * 33 + c];
        *(f16*)((char*)sDin + m * 128 + ((2 * c) ^ ((m & 7) << 4))) = (f16)v;
      }
      __syncthreads();
    }
    ph ^= 1;
  }
}

// ---------------- launcher ----------------
extern "C" void kernel_launch(void* const* d_in, const int* in_sizes, int n_in,
                              void* d_out, int out_size, void* d_ws, size_t ws_size,
                              hipStream_t stream) {
  char* ws = (char*)d_ws;
  P p;
  p.Xe   = (const float*)d_in[0];
  p.Xd   = (const float*)d_in[1];
  p.Xge  = (const float*)d_in[2];
  p.Xgd  = (const float*)d_in[3];
  p.Wge  = (const float*)d_in[4];
  p.bge  = (const float*)d_in[5];
  p.Wgd  = (const float*)d_in[6];
  p.bgd  = (const float*)d_in[7];
  p.eWih = (const float*)d_in[8];
  p.eWhh = (const float*)d_in[9];
  p.ebih = (const float*)d_in[10];
  p.ebhh = (const float*)d_in[11];
  p.eWo  = (const float*)d_in[12];
  p.ebo  = (const float*)d_in[13];
  p.dWih = (const float*)d_in[14];
  p.dWhh = (const float*)d_in[15];
  p.dbih = (const float*)d_in[16];
  p.dbhh = (const float*)d_in[17];
  p.dWo  = (const float*)d_in[18];
  p.dbo  = (const float*)d_in[19];
  p.bn1g = (const float*)d_in[20];
  p.bn1b = (const float*)d_in[21];
  p.bnTg = (const float*)d_in[22];
  p.bnTb = (const float*)d_in[23];
  p.encin = (f16*)(ws + OFF_ENCIN);
  p.decin = (f16*)(ws + OFF_DECIN);
  p.wencf = (f16*)(ws + OFF_WENC);
  p.wdecf = (f16*)(ws + OFF_WDEC);
  p.w32   = (float*)(ws + OFF_W32);
  p.bE    = (float*)(ws + OFF_BE);
  p.bD    = (float*)(ws + OFF_BD);
  p.henc  = (f16*)(ws + OFF_HENC);
  p.eout  = (float*)(ws + OFF_EOUT);
  p.xst   = (float*)(ws + OFF_XST);
  p.ost   = (float*)(ws + OFF_OST);
  p.bar   = (int*)(ws + OFF_BAR);
  p.out   = (float*)d_out;

  prep1<<<dim3(1291), dim3(256), 0, stream>>>(p);
  prep2<<<dim3(6), dim3(256), 0, stream>>>(p);
  enc_kernel<<<dim3(16), dim3(512), 0, stream>>>(p);
  dec_kernel<<<dim3(16), dim3(512), 0, stream>>>(p);
}